// Round 1
// baseline (75.280 us; speedup 1.0000x reference)
//
#include <hip/hip_runtime.h>

// SpikeLN: per-row (len 768) mean removal, variance, tiny-MLP "1/sqrt" scalar,
// scale + affine. One 64-lane wave per row; 12 f32/lane in registers.

#define ROW_N 768   // elements per row
#define NEUR  8     // hidden neurons in distilled MLP

__global__ __launch_bounds__(256) void spikeln_kernel(
    const float* __restrict__ x,
    const float* __restrict__ w1,    // [8]
    const float* __restrict__ b1,    // [8]
    const float* __restrict__ w2,    // [8]
    const float* __restrict__ b2,    // [1]
    const float* __restrict__ gamma, // [768]
    const float* __restrict__ beta,  // [768]
    float* __restrict__ out,
    int rows)
{
    const int gid  = blockIdx.x * blockDim.x + threadIdx.x;
    const int row  = gid >> 6;
    const int lane = threadIdx.x & 63;
    if (row >= rows) return;

    const float4* xv = reinterpret_cast<const float4*>(x + (size_t)row * ROW_N);
    float4 v0 = xv[lane];
    float4 v1 = xv[lane + 64];
    float4 v2 = xv[lane + 128];

    // ---- pass 1: mean ----
    float s = ((v0.x + v0.y) + (v0.z + v0.w))
            + ((v1.x + v1.y) + (v1.z + v1.w))
            + ((v2.x + v2.y) + (v2.z + v2.w));
    #pragma unroll
    for (int off = 32; off > 0; off >>= 1)
        s += __shfl_xor(s, off, 64);
    const float mean = s * (1.0f / ROW_N);

    // ---- pass 2 (registers): center + sum of squares ----
    v0.x -= mean; v0.y -= mean; v0.z -= mean; v0.w -= mean;
    v1.x -= mean; v1.y -= mean; v1.z -= mean; v1.w -= mean;
    v2.x -= mean; v2.y -= mean; v2.z -= mean; v2.w -= mean;

    float ss = ((v0.x * v0.x + v0.y * v0.y) + (v0.z * v0.z + v0.w * v0.w))
             + ((v1.x * v1.x + v1.y * v1.y) + (v1.z * v1.z + v1.w * v1.w))
             + ((v2.x * v2.x + v2.y * v2.y) + (v2.z * v2.z + v2.w * v2.w));
    #pragma unroll
    for (int off = 32; off > 0; off >>= 1)
        ss += __shfl_xor(ss, off, 64);
    const float var = ss * (1.0f / ROW_N);

    // ---- distilled sqrt-inverse MLP (redundant per-lane; uniform loads) ----
    float rec = b2[0];
    #pragma unroll
    for (int j = 0; j < NEUR; ++j)
        rec += fmaxf(fmaf(var, w1[j], b1[j]), 0.0f) * w2[j];

    // ---- scale + affine, vectorized store ----
    const float4* gv = reinterpret_cast<const float4*>(gamma);
    const float4* bv = reinterpret_cast<const float4*>(beta);
    float4*       ov = reinterpret_cast<float4*>(out + (size_t)row * ROW_N);

    float4 g, bb, o;

    g = gv[lane]; bb = bv[lane];
    o.x = fmaf(v0.x * rec, g.x, bb.x);
    o.y = fmaf(v0.y * rec, g.y, bb.y);
    o.z = fmaf(v0.z * rec, g.z, bb.z);
    o.w = fmaf(v0.w * rec, g.w, bb.w);
    ov[lane] = o;

    g = gv[lane + 64]; bb = bv[lane + 64];
    o.x = fmaf(v1.x * rec, g.x, bb.x);
    o.y = fmaf(v1.y * rec, g.y, bb.y);
    o.z = fmaf(v1.z * rec, g.z, bb.z);
    o.w = fmaf(v1.w * rec, g.w, bb.w);
    ov[lane + 64] = o;

    g = gv[lane + 128]; bb = bv[lane + 128];
    o.x = fmaf(v2.x * rec, g.x, bb.x);
    o.y = fmaf(v2.y * rec, g.y, bb.y);
    o.z = fmaf(v2.z * rec, g.z, bb.z);
    o.w = fmaf(v2.w * rec, g.w, bb.w);
    ov[lane + 128] = o;
}

extern "C" void kernel_launch(void* const* d_in, const int* in_sizes, int n_in,
                              void* d_out, int out_size, void* d_ws, size_t ws_size,
                              hipStream_t stream) {
    const float* x     = (const float*)d_in[0];
    const float* w1    = (const float*)d_in[1];
    const float* b1    = (const float*)d_in[2];
    const float* w2    = (const float*)d_in[3];
    const float* b2    = (const float*)d_in[4];
    const float* gamma = (const float*)d_in[5];
    const float* beta  = (const float*)d_in[6];
    float* out = (float*)d_out;

    const int rows = in_sizes[0] / ROW_N;           // 65536
    const int waves_per_block = 256 / 64;           // 4 rows per block
    const int blocks = (rows + waves_per_block - 1) / waves_per_block;

    spikeln_kernel<<<blocks, 256, 0, stream>>>(x, w1, b1, w2, b2, gamma, beta,
                                               out, rows);
}

// Round 3
// 68.244 us; speedup vs baseline: 1.1031x; 1.1031x over previous
//
#include <hip/hip_runtime.h>

// SpikeLN: per-row (len 768) mean removal, variance, tiny-MLP "1/sqrt" scalar,
// scale + affine. One 64-lane wave per row; 12 f32/lane in registers.
// v3: single-pass moments (E[x^2] - mean^2), nontemporal x/out streams,
//     ext_vector_type for the nontemporal builtins.

#define ROW_N 768   // elements per row
#define NEUR  8     // hidden neurons in distilled MLP

typedef float f32x4 __attribute__((ext_vector_type(4)));

__global__ __launch_bounds__(256) void spikeln_kernel(
    const float* __restrict__ x,
    const float* __restrict__ w1,    // [8]
    const float* __restrict__ b1,    // [8]
    const float* __restrict__ w2,    // [8]
    const float* __restrict__ b2,    // [1]
    const float* __restrict__ gamma, // [768]
    const float* __restrict__ beta,  // [768]
    float* __restrict__ out,
    int rows)
{
    const int gid  = blockIdx.x * blockDim.x + threadIdx.x;
    const int row  = gid >> 6;
    const int lane = threadIdx.x & 63;
    if (row >= rows) return;

    const f32x4* xv = reinterpret_cast<const f32x4*>(x + (size_t)row * ROW_N);
    // streamed once — nontemporal
    f32x4 v0 = __builtin_nontemporal_load(&xv[lane]);
    f32x4 v1 = __builtin_nontemporal_load(&xv[lane + 64]);
    f32x4 v2 = __builtin_nontemporal_load(&xv[lane + 128]);

    // gamma/beta: cached (reused by every row); issue early to overlap
    const f32x4* gv = reinterpret_cast<const f32x4*>(gamma);
    const f32x4* bv = reinterpret_cast<const f32x4*>(beta);
    f32x4 g0 = gv[lane],       c0 = bv[lane];
    f32x4 g1 = gv[lane + 64],  c1 = bv[lane + 64];
    f32x4 g2 = gv[lane + 128], c2 = bv[lane + 128];

    // ---- single pass: sum and sum of squares ----
    float s  = ((v0.x + v0.y) + (v0.z + v0.w))
             + ((v1.x + v1.y) + (v1.z + v1.w))
             + ((v2.x + v2.y) + (v2.z + v2.w));
    float ss = ((v0.x * v0.x + v0.y * v0.y) + (v0.z * v0.z + v0.w * v0.w))
             + ((v1.x * v1.x + v1.y * v1.y) + (v1.z * v1.z + v1.w * v1.w))
             + ((v2.x * v2.x + v2.y * v2.y) + (v2.z * v2.z + v2.w * v2.w));
    #pragma unroll
    for (int off = 32; off > 0; off >>= 1) {
        s  += __shfl_xor(s,  off, 64);   // two independent chains,
        ss += __shfl_xor(ss, off, 64);   // interleaved
    }
    const float mean = s * (1.0f / ROW_N);
    const float var  = fmaf(-mean, mean, ss * (1.0f / ROW_N)); // E[x^2]-mean^2

    // ---- distilled sqrt-inverse MLP (redundant per-lane; uniform loads) ----
    float rec = b2[0];
    #pragma unroll
    for (int j = 0; j < NEUR; ++j)
        rec += fmaxf(fmaf(var, w1[j], b1[j]), 0.0f) * w2[j];

    // ---- out = (x - mean) * rec * gamma + beta, nontemporal store ----
    f32x4* ov = reinterpret_cast<f32x4*>(out + (size_t)row * ROW_N);
    f32x4 o;

    o.x = fmaf((v0.x - mean) * rec, g0.x, c0.x);
    o.y = fmaf((v0.y - mean) * rec, g0.y, c0.y);
    o.z = fmaf((v0.z - mean) * rec, g0.z, c0.z);
    o.w = fmaf((v0.w - mean) * rec, g0.w, c0.w);
    __builtin_nontemporal_store(o, &ov[lane]);

    o.x = fmaf((v1.x - mean) * rec, g1.x, c1.x);
    o.y = fmaf((v1.y - mean) * rec, g1.y, c1.y);
    o.z = fmaf((v1.z - mean) * rec, g1.z, c1.z);
    o.w = fmaf((v1.w - mean) * rec, g1.w, c1.w);
    __builtin_nontemporal_store(o, &ov[lane + 64]);

    o.x = fmaf((v2.x - mean) * rec, g2.x, c2.x);
    o.y = fmaf((v2.y - mean) * rec, g2.y, c2.y);
    o.z = fmaf((v2.z - mean) * rec, g2.z, c2.z);
    o.w = fmaf((v2.w - mean) * rec, g2.w, c2.w);
    __builtin_nontemporal_store(o, &ov[lane + 128]);
}

extern "C" void kernel_launch(void* const* d_in, const int* in_sizes, int n_in,
                              void* d_out, int out_size, void* d_ws, size_t ws_size,
                              hipStream_t stream) {
    const float* x     = (const float*)d_in[0];
    const float* w1    = (const float*)d_in[1];
    const float* b1    = (const float*)d_in[2];
    const float* w2    = (const float*)d_in[3];
    const float* b2    = (const float*)d_in[4];
    const float* gamma = (const float*)d_in[5];
    const float* beta  = (const float*)d_in[6];
    float* out = (float*)d_out;

    const int rows = in_sizes[0] / ROW_N;           // 65536
    const int waves_per_block = 256 / 64;           // 4 rows per block
    const int blocks = (rows + waves_per_block - 1) / waves_per_block;

    spikeln_kernel<<<blocks, 256, 0, stream>>>(x, w1, b1, w2, b2, gamma, beta,
                                               out, rows);
}